// Round 1
// baseline (977.798 us; speedup 1.0000x reference)
//
#include <hip/hip_runtime.h>

#define LEAKY 0.2f

__device__ __forceinline__ int enc_f(float f) {
  int i = __float_as_int(f);
  return i >= 0 ? i : i ^ 0x7fffffff;
}
__device__ __forceinline__ float dec_f(int i) {
  return __int_as_float(i >= 0 ? i : i ^ 0x7fffffff);
}

// ---------------- CSR build ----------------
__global__ void count_k(const int* __restrict__ dst, int* __restrict__ cnt, int E) {
  int i = blockIdx.x * blockDim.x + threadIdx.x;
  if (i < E) atomicAdd(&cnt[dst[i]], 1);
}

__global__ __launch_bounds__(1024) void scan_k(const int* __restrict__ cnt,
                                               int* __restrict__ ptr, int N, int E) {
  __shared__ int buf[1024];
  __shared__ int carry_s;
  int t = threadIdx.x;
  if (t == 0) carry_s = 0;
  __syncthreads();
  for (int base = 0; base < N; base += 1024) {
    int i = base + t;
    int v = (i < N) ? cnt[i] : 0;
    buf[t] = v;
    __syncthreads();
    for (int off = 1; off < 1024; off <<= 1) {
      int tmp = (t >= off) ? buf[t - off] : 0;
      __syncthreads();
      buf[t] += tmp;
      __syncthreads();
    }
    int incl = buf[t];
    if (i < N) ptr[i] = carry_s + incl - v;  // exclusive
    __syncthreads();
    if (t == 0) carry_s += buf[1023];
    __syncthreads();
  }
  if (t == 0) ptr[N] = E;
}

__global__ void fill_k(const int* __restrict__ dst, const int* __restrict__ ptr,
                       int* __restrict__ cur, int* __restrict__ eidx, int E) {
  int i = blockIdx.x * blockDim.x + threadIdx.x;
  if (i < E) {
    int d = dst[i];
    int p = atomicAdd(&cur[d], 1);
    eidx[ptr[d] + p] = i;
  }
}

// ---------------- GEMM: C[N][256] = A[N][K] @ B[K][256], f32 ----------------
__global__ __launch_bounds__(256) void gemm_k(const float* __restrict__ A,
                                              const float* __restrict__ B,
                                              float* __restrict__ C, int N, int K) {
  __shared__ float As[32][65];  // As[k][r], padded
  __shared__ float Bs[32][64];  // Bs[k][c]
  int t = threadIdx.x;
  int row0 = blockIdx.x * 64;
  int col0 = blockIdx.y * 64;
  int rbase = (t >> 4) * 4;
  int cbase = (t & 15) * 4;
  float acc[4][4] = {};
  for (int k0 = 0; k0 < K; k0 += 32) {
    // load A tile: 64 rows x 32 k, transpose into As
    {
      int r = t >> 2;
      #pragma unroll
      for (int it = 0; it < 2; ++it) {
        int f = (t & 3) + it * 4;  // float4 index 0..7
        float4 v = *(const float4*)(A + (long)(row0 + r) * K + k0 + f * 4);
        As[f * 4 + 0][r] = v.x;
        As[f * 4 + 1][r] = v.y;
        As[f * 4 + 2][r] = v.z;
        As[f * 4 + 3][r] = v.w;
      }
    }
    // load B tile: 32 k x 64 c
    {
      #pragma unroll
      for (int it = 0; it < 2; ++it) {
        int kk = (t >> 4) + it * 16;
        int c = (t & 15) * 4;
        float4 v = *(const float4*)(B + (long)(k0 + kk) * 256 + col0 + c);
        *(float4*)&Bs[kk][c] = v;
      }
    }
    __syncthreads();
    #pragma unroll 8
    for (int k = 0; k < 32; ++k) {
      float4 b = *(const float4*)&Bs[k][cbase];
      float a0 = As[k][rbase + 0];
      float a1 = As[k][rbase + 1];
      float a2 = As[k][rbase + 2];
      float a3 = As[k][rbase + 3];
      acc[0][0] += a0 * b.x; acc[0][1] += a0 * b.y; acc[0][2] += a0 * b.z; acc[0][3] += a0 * b.w;
      acc[1][0] += a1 * b.x; acc[1][1] += a1 * b.y; acc[1][2] += a1 * b.z; acc[1][3] += a1 * b.w;
      acc[2][0] += a2 * b.x; acc[2][1] += a2 * b.y; acc[2][2] += a2 * b.z; acc[2][3] += a2 * b.w;
      acc[3][0] += a3 * b.x; acc[3][1] += a3 * b.y; acc[3][2] += a3 * b.z; acc[3][3] += a3 * b.w;
    }
    __syncthreads();
  }
  #pragma unroll
  for (int i = 0; i < 4; ++i) {
    float4 v = make_float4(acc[i][0], acc[i][1], acc[i][2], acc[i][3]);
    *(float4*)(C + (long)(row0 + rbase + i) * 256 + col0 + cbase) = v;
  }
}

// ---------------- el/er: per (node, head) dot with attn vectors ----------------
__global__ void eler_k(const float* __restrict__ h, const float* __restrict__ al,
                       const float* __restrict__ ar, float* __restrict__ el,
                       float* __restrict__ er, int N) {
  int i = blockIdx.x * blockDim.x + threadIdx.x;
  if (i >= N * 8) return;
  int n = i >> 3, hh = i & 7;
  const float4* hp = (const float4*)(h + (long)n * 256 + hh * 32);
  const float4* alp = (const float4*)(al + hh * 32);
  const float4* arp = (const float4*)(ar + hh * 32);
  float sl = 0.f, sr = 0.f;
  #pragma unroll
  for (int q = 0; q < 8; ++q) {
    float4 hv = hp[q], a = alp[q], b = arp[q];
    sl += hv.x * a.x + hv.y * a.y + hv.z * a.z + hv.w * a.w;
    sr += hv.x * b.x + hv.y * b.y + hv.z * b.z + hv.w * b.w;
  }
  el[i] = sl;
  er[i] = sr;
}

// ---------------- per-dst-node edge softmax + aggregate ----------------
__global__ __launch_bounds__(256) void agg_k(const float* __restrict__ hlin,
                                             const float* __restrict__ el,
                                             const float* __restrict__ er,
                                             const int* __restrict__ ptr,
                                             const int* __restrict__ eidx,
                                             const int* __restrict__ src,
                                             float* __restrict__ out, int N) {
  int n = blockIdx.x;
  int t = threadIdx.x;
  int beg = ptr[n], end = ptr[n + 1];
  int deg = end - beg;
  if (deg == 0) {
    out[(long)n * 256 + t] = 0.f;
    return;
  }
  __shared__ float er_s[8];
  __shared__ int smax[8];
  __shared__ float ssum[8];
  __shared__ float m_s[8], inv_s[8];
  __shared__ int sid[64];
  __shared__ float a_s[64][8];
  if (t < 8) {
    er_s[t] = er[(long)n * 8 + t];
    smax[t] = 0x80000000;  // -inf encoded floor
    ssum[t] = 0.f;
  }
  __syncthreads();
  // phase A1: per-head max over incoming edges
  for (int i = t; i < deg * 8; i += 256) {
    int e = i >> 3, hh = i & 7;
    int s = src[eidx[beg + e]];
    float v = el[(long)s * 8 + hh] + er_s[hh];
    v = v > 0.f ? v : LEAKY * v;
    atomicMax(&smax[hh], enc_f(v));
  }
  __syncthreads();
  if (t < 8) m_s[t] = dec_f(smax[t]);
  __syncthreads();
  // phase A2: per-head sum of exp(e - m)
  for (int i = t; i < deg * 8; i += 256) {
    int e = i >> 3, hh = i & 7;
    int s = src[eidx[beg + e]];
    float v = el[(long)s * 8 + hh] + er_s[hh];
    v = v > 0.f ? v : LEAKY * v;
    atomicAdd(&ssum[hh], __expf(v - m_s[hh]));
  }
  __syncthreads();
  if (t < 8) inv_s[t] = 1.0f / ssum[t];
  __syncthreads();
  // phase B: accumulate attention-weighted messages, chunked by 64 edges
  float acc = 0.f;
  int hh = t >> 5;
  for (int c0 = 0; c0 < deg; c0 += 64) {
    int clen = min(64, deg - c0);
    if (t < clen) sid[t] = src[eidx[beg + c0 + t]];
    __syncthreads();
    for (int i = t; i < clen * 8; i += 256) {
      int e = i >> 3, h2 = i & 7;
      int s = sid[e];
      float v = el[(long)s * 8 + h2] + er_s[h2];
      v = v > 0.f ? v : LEAKY * v;
      a_s[e][h2] = __expf(v - m_s[h2]) * inv_s[h2];
    }
    __syncthreads();
    for (int e = 0; e < clen; ++e) {
      acc += a_s[e][hh] * hlin[(long)sid[e] * 256 + t];
    }
    __syncthreads();
  }
  out[(long)n * 256 + t] = acc;
}

// ---------------- per-graph mean pooling (graph_ids sorted) ----------------
__device__ __forceinline__ int lower_bound_i(const int* a, int n, int key) {
  int lo = 0, hi = n;
  while (lo < hi) {
    int mid = (lo + hi) >> 1;
    if (a[mid] < key) lo = mid + 1; else hi = mid;
  }
  return lo;
}

__global__ __launch_bounds__(256) void pool_k(const float* __restrict__ h,
                                              const int* __restrict__ gid,
                                              float* __restrict__ pooled, int N, int G) {
  int g = blockIdx.x;
  int t = threadIdx.x;
  __shared__ int s_lo, s_hi;
  if (t == 0) {
    s_lo = lower_bound_i(gid, N, g);
    s_hi = lower_bound_i(gid, N, g + 1);
  }
  __syncthreads();
  int lo = s_lo, hi = s_hi;
  float acc = 0.f;
  for (int n = lo; n < hi; ++n) acc += h[(long)n * 256 + t];
  float c = (float)(hi - lo);
  pooled[g * 256 + t] = acc / fmaxf(c, 1.f);
}

// ---------------- MLP: Dense(512,relu) -> Dense(1) fused ----------------
__global__ __launch_bounds__(256) void mlp_k(const float* __restrict__ pooled,
                                             const float* __restrict__ Wd1,
                                             const float* __restrict__ bd1,
                                             const float* __restrict__ Wd2,
                                             const float* __restrict__ bd2,
                                             float* __restrict__ outv, int G) {
  int g = blockIdx.x;
  int t = threadIdx.x;
  __shared__ float p_s[256];
  __shared__ float red[256];
  p_s[t] = pooled[g * 256 + t];
  __syncthreads();
  float acc0 = bd1[t], acc1 = bd1[t + 256];
  for (int k = 0; k < 256; ++k) {
    float pv = p_s[k];
    acc0 += pv * Wd1[k * 512 + t];
    acc1 += pv * Wd1[k * 512 + t + 256];
  }
  acc0 = fmaxf(acc0, 0.f);
  acc1 = fmaxf(acc1, 0.f);
  red[t] = acc0 * Wd2[t] + acc1 * Wd2[t + 256];
  __syncthreads();
  for (int off = 128; off > 0; off >>= 1) {
    if (t < off) red[t] += red[t + off];
    __syncthreads();
  }
  if (t == 0) outv[g] = red[0] + bd2[0];
}

extern "C" void kernel_launch(void* const* d_in, const int* in_sizes, int n_in,
                              void* d_out, int out_size, void* d_ws, size_t ws_size,
                              hipStream_t stream) {
  const float* X   = (const float*)d_in[0];
  const int*   src = (const int*)d_in[1];
  const int*   dst = (const int*)d_in[2];
  const int*   gid = (const int*)d_in[3];
  const float* W0  = (const float*)d_in[5];
  const float* al0 = (const float*)d_in[6];
  const float* ar0 = (const float*)d_in[7];
  const float* W1  = (const float*)d_in[8];
  const float* al1 = (const float*)d_in[9];
  const float* ar1 = (const float*)d_in[10];
  const float* Wd1 = (const float*)d_in[11];
  const float* bd1 = (const float*)d_in[12];
  const float* Wd2 = (const float*)d_in[13];
  const float* bd2 = (const float*)d_in[14];

  int E = in_sizes[1];
  int N = in_sizes[3];
  int G = out_size;

  float* bufA   = (float*)d_ws;                    // [N,256] GEMM out (h_lin)
  float* bufB   = bufA + (size_t)N * 256;          // [N,256] agg out
  float* el     = bufB + (size_t)N * 256;          // [N,8]
  float* er     = el + (size_t)N * 8;              // [N,8]
  float* pooled = er + (size_t)N * 8;              // [G,256]
  int*   ptr    = (int*)(pooled + (size_t)G * 256);  // [N+1]
  int*   cnt    = ptr + (N + 1);                   // [N] counts, then cursor
  int*   eidx   = cnt + N;                         // [E]

  // CSR build over dst
  hipMemsetAsync(cnt, 0, (size_t)N * 4, stream);
  count_k<<<(E + 255) / 256, 256, 0, stream>>>(dst, cnt, E);
  scan_k<<<1, 1024, 0, stream>>>(cnt, ptr, N, E);
  hipMemsetAsync(cnt, 0, (size_t)N * 4, stream);
  fill_k<<<(E + 255) / 256, 256, 0, stream>>>(dst, ptr, cnt, eidx, E);

  dim3 gg(N / 64, 4);
  // layer 0
  gemm_k<<<gg, 256, 0, stream>>>(X, W0, bufA, N, 128);
  eler_k<<<(N * 8 + 255) / 256, 256, 0, stream>>>(bufA, al0, ar0, el, er, N);
  agg_k<<<N, 256, 0, stream>>>(bufA, el, er, ptr, eidx, src, bufB, N);
  // layer 1
  gemm_k<<<gg, 256, 0, stream>>>(bufB, W1, bufA, N, 256);
  eler_k<<<(N * 8 + 255) / 256, 256, 0, stream>>>(bufA, al1, ar1, el, er, N);
  agg_k<<<N, 256, 0, stream>>>(bufA, el, er, ptr, eidx, src, bufB, N);
  // readout + MLP
  pool_k<<<G, 256, 0, stream>>>(bufB, gid, pooled, N, G);
  mlp_k<<<G, 256, 0, stream>>>(pooled, Wd1, bd1, Wd2, bd2, (float*)d_out, G);
}

// Round 2
// 818.114 us; speedup vs baseline: 1.1952x; 1.1952x over previous
//
#include <hip/hip_runtime.h>

#define LEAKY 0.2f

__device__ __forceinline__ int enc_f(float f) {
  int i = __float_as_int(f);
  return i >= 0 ? i : i ^ 0x7fffffff;
}
__device__ __forceinline__ float dec_f(int i) {
  return __int_as_float(i >= 0 ? i : i ^ 0x7fffffff);
}

// ---------------- CSR build ----------------
__global__ void count_k(const int* __restrict__ dst, int* __restrict__ cnt, int E) {
  int i = blockIdx.x * blockDim.x + threadIdx.x;
  if (i < E) atomicAdd(&cnt[dst[i]], 1);
}

// hierarchical scan: 64 blocks x 1024 -> bsum[64] -> offsets
__global__ __launch_bounds__(1024) void scan1_k(const int* __restrict__ cnt,
                                                int* __restrict__ ptr,
                                                int* __restrict__ bsum, int N) {
  int t = threadIdx.x;
  int i = blockIdx.x * 1024 + t;
  int v = (i < N) ? cnt[i] : 0;
  int lane = t & 63, w = t >> 6;
  int x = v;
  #pragma unroll
  for (int off = 1; off < 64; off <<= 1) {
    int y = __shfl_up(x, off, 64);
    if (lane >= off) x += y;
  }
  __shared__ int wsum[16];
  if (lane == 63) wsum[w] = x;
  __syncthreads();
  if (t < 16) {
    int s = wsum[t];
    #pragma unroll
    for (int off = 1; off < 16; off <<= 1) {
      int y = __shfl_up(s, off, 16);
      if (t >= off) s += y;
    }
    wsum[t] = s;
  }
  __syncthreads();
  int woff = (w > 0) ? wsum[w - 1] : 0;
  int incl = x + woff;
  if (i < N) ptr[i] = incl - v;  // local exclusive
  if (t == 1023) bsum[blockIdx.x] = incl;
}

__global__ void scan2_k(int* __restrict__ bsum, int nb) {
  int t = threadIdx.x;
  int v = (t < nb) ? bsum[t] : 0;
  int x = v;
  #pragma unroll
  for (int off = 1; off < 64; off <<= 1) {
    int y = __shfl_up(x, off, 64);
    if (t >= off) x += y;
  }
  if (t < nb) bsum[t] = x - v;  // exclusive block offsets
}

__global__ __launch_bounds__(1024) void scan3_k(int* __restrict__ ptr,
                                                const int* __restrict__ bsum,
                                                int N, int E) {
  int i = blockIdx.x * 1024 + threadIdx.x;
  if (i < N) ptr[i] += bsum[blockIdx.x];
  if (i == 0) ptr[N] = E;
}

__global__ void fill_k(const int* __restrict__ dst, const int* __restrict__ ptr,
                       int* __restrict__ cur, int* __restrict__ eidx, int E) {
  int i = blockIdx.x * blockDim.x + threadIdx.x;
  if (i < E) {
    int d = dst[i];
    int p = atomicAdd(&cur[d], 1);
    eidx[ptr[d] + p] = i;
  }
}

// ---------------- GEMM: C[N][256] = A[N][K] @ B[K][256], f32 ----------------
__global__ __launch_bounds__(256) void gemm_k(const float* __restrict__ A,
                                              const float* __restrict__ B,
                                              float* __restrict__ C, int N, int K) {
  __shared__ float As[32][65];  // As[k][r], padded
  __shared__ float Bs[32][64];  // Bs[k][c]
  int t = threadIdx.x;
  int row0 = blockIdx.x * 64;
  int col0 = blockIdx.y * 64;
  int rbase = (t >> 4) * 4;
  int cbase = (t & 15) * 4;
  float acc[4][4] = {};
  for (int k0 = 0; k0 < K; k0 += 32) {
    {
      int r = t >> 2;
      #pragma unroll
      for (int it = 0; it < 2; ++it) {
        int f = (t & 3) + it * 4;
        float4 v = *(const float4*)(A + (long)(row0 + r) * K + k0 + f * 4);
        As[f * 4 + 0][r] = v.x;
        As[f * 4 + 1][r] = v.y;
        As[f * 4 + 2][r] = v.z;
        As[f * 4 + 3][r] = v.w;
      }
    }
    {
      #pragma unroll
      for (int it = 0; it < 2; ++it) {
        int kk = (t >> 4) + it * 16;
        int c = (t & 15) * 4;
        float4 v = *(const float4*)(B + (long)(k0 + kk) * 256 + col0 + c);
        *(float4*)&Bs[kk][c] = v;
      }
    }
    __syncthreads();
    #pragma unroll 8
    for (int k = 0; k < 32; ++k) {
      float4 b = *(const float4*)&Bs[k][cbase];
      float a0 = As[k][rbase + 0];
      float a1 = As[k][rbase + 1];
      float a2 = As[k][rbase + 2];
      float a3 = As[k][rbase + 3];
      acc[0][0] += a0 * b.x; acc[0][1] += a0 * b.y; acc[0][2] += a0 * b.z; acc[0][3] += a0 * b.w;
      acc[1][0] += a1 * b.x; acc[1][1] += a1 * b.y; acc[1][2] += a1 * b.z; acc[1][3] += a1 * b.w;
      acc[2][0] += a2 * b.x; acc[2][1] += a2 * b.y; acc[2][2] += a2 * b.z; acc[2][3] += a2 * b.w;
      acc[3][0] += a3 * b.x; acc[3][1] += a3 * b.y; acc[3][2] += a3 * b.z; acc[3][3] += a3 * b.w;
    }
    __syncthreads();
  }
  #pragma unroll
  for (int i = 0; i < 4; ++i) {
    float4 v = make_float4(acc[i][0], acc[i][1], acc[i][2], acc[i][3]);
    *(float4*)(C + (long)(row0 + rbase + i) * 256 + col0 + cbase) = v;
  }
}

// ---------------- el/er: per (node, head) dot with attn vectors ----------------
__global__ void eler_k(const float* __restrict__ h, const float* __restrict__ al,
                       const float* __restrict__ ar, float* __restrict__ el,
                       float* __restrict__ er, int N) {
  int i = blockIdx.x * blockDim.x + threadIdx.x;
  if (i >= N * 8) return;
  int n = i >> 3, hh = i & 7;
  const float4* hp = (const float4*)(h + (long)n * 256 + hh * 32);
  const float4* alp = (const float4*)(al + hh * 32);
  const float4* arp = (const float4*)(ar + hh * 32);
  float sl = 0.f, sr = 0.f;
  #pragma unroll
  for (int q = 0; q < 8; ++q) {
    float4 hv = hp[q], a = alp[q], b = arp[q];
    sl += hv.x * a.x + hv.y * a.y + hv.z * a.z + hv.w * a.w;
    sr += hv.x * b.x + hv.y * b.y + hv.z * b.z + hv.w * b.w;
  }
  el[i] = sl;
  er[i] = sr;
}

// ---------------- per-dst-node edge softmax + aggregate ----------------
// Block = 4 waves x 64 lanes. Lane l owns cols 4l..4l+3 (float4 gather),
// wave g handles edges e == g (mod 4) -> 4x memory-level parallelism.
__global__ __launch_bounds__(256) void agg_k(const float* __restrict__ hlin,
                                             const float* __restrict__ el,
                                             const float* __restrict__ er,
                                             const int* __restrict__ ptr,
                                             const int* __restrict__ eidx,
                                             const int* __restrict__ src,
                                             float* __restrict__ out, int N) {
  int n = blockIdx.x;
  int t = threadIdx.x;
  int beg = ptr[n], end = ptr[n + 1];
  int deg = end - beg;
  if (deg == 0) {
    out[(long)n * 256 + t] = 0.f;
    return;
  }
  __shared__ float er_s[8];
  __shared__ int smax[8];
  __shared__ float ssum[8];
  __shared__ float m_s[8], inv_s[8];
  __shared__ int sid[64];
  __shared__ float a_s[64][8];
  __shared__ float part[4][256];
  if (t < 8) {
    er_s[t] = er[(long)n * 8 + t];
    smax[t] = 0x80000000;
    ssum[t] = 0.f;
  }
  __syncthreads();
  bool fast = (deg <= 64);
  if (fast) {
    // single chunk: gather el once, keep logits in LDS
    if (t < deg) sid[t] = src[eidx[beg + t]];
    __syncthreads();
    for (int i = t; i < deg * 8; i += 256) {
      int e = i >> 3, hh = i & 7;
      float v = el[(long)sid[e] * 8 + hh] + er_s[hh];
      v = v > 0.f ? v : LEAKY * v;
      a_s[e][hh] = v;
      atomicMax(&smax[hh], enc_f(v));
    }
    __syncthreads();
    if (t < 8) m_s[t] = dec_f(smax[t]);
    __syncthreads();
    for (int i = t; i < deg * 8; i += 256) {
      int e = i >> 3, hh = i & 7;
      float ex = __expf(a_s[e][hh] - m_s[hh]);
      a_s[e][hh] = ex;
      atomicAdd(&ssum[hh], ex);
    }
    __syncthreads();
    if (t < 8) inv_s[t] = 1.0f / ssum[t];
    __syncthreads();
    for (int i = t; i < deg * 8; i += 256) {
      int e = i >> 3, hh = i & 7;
      a_s[e][hh] *= inv_s[hh];
    }
    __syncthreads();
  } else {
    // generic multi-chunk path (rare: deg > 64)
    for (int i = t; i < deg * 8; i += 256) {
      int e = i >> 3, hh = i & 7;
      int s = src[eidx[beg + e]];
      float v = el[(long)s * 8 + hh] + er_s[hh];
      v = v > 0.f ? v : LEAKY * v;
      atomicMax(&smax[hh], enc_f(v));
    }
    __syncthreads();
    if (t < 8) m_s[t] = dec_f(smax[t]);
    __syncthreads();
    for (int i = t; i < deg * 8; i += 256) {
      int e = i >> 3, hh = i & 7;
      int s = src[eidx[beg + e]];
      float v = el[(long)s * 8 + hh] + er_s[hh];
      v = v > 0.f ? v : LEAKY * v;
      atomicAdd(&ssum[hh], __expf(v - m_s[hh]));
    }
    __syncthreads();
    if (t < 8) inv_s[t] = 1.0f / ssum[t];
    __syncthreads();
  }
  // phase B: wave-parallel weighted gather
  int g = t >> 6, l = t & 63, hh = l >> 3;
  float ax = 0.f, ay = 0.f, az = 0.f, aw = 0.f;
  for (int c0 = 0; c0 < deg; c0 += 64) {
    int clen = min(64, deg - c0);
    if (!fast) {
      __syncthreads();
      if (t < clen) sid[t] = src[eidx[beg + c0 + t]];
      __syncthreads();
      for (int i = t; i < clen * 8; i += 256) {
        int e = i >> 3, h2 = i & 7;
        float v = el[(long)sid[e] * 8 + h2] + er_s[h2];
        v = v > 0.f ? v : LEAKY * v;
        a_s[e][h2] = __expf(v - m_s[h2]) * inv_s[h2];
      }
      __syncthreads();
    }
    for (int e = g; e < clen; e += 4) {
      float a = a_s[e][hh];
      const float4 hv = *(const float4*)(hlin + (long)sid[e] * 256 + l * 4);
      ax += a * hv.x;
      ay += a * hv.y;
      az += a * hv.z;
      aw += a * hv.w;
    }
  }
  *(float4*)&part[g][l * 4] = make_float4(ax, ay, az, aw);
  __syncthreads();
  out[(long)n * 256 + t] = part[0][t] + part[1][t] + part[2][t] + part[3][t];
}

// ---------------- per-graph mean pooling (graph_ids sorted) ----------------
__device__ __forceinline__ int lower_bound_i(const int* a, int n, int key) {
  int lo = 0, hi = n;
  while (lo < hi) {
    int mid = (lo + hi) >> 1;
    if (a[mid] < key) lo = mid + 1; else hi = mid;
  }
  return lo;
}

__global__ __launch_bounds__(256) void pool_k(const float* __restrict__ h,
                                              const int* __restrict__ gid,
                                              float* __restrict__ pooled, int N, int G) {
  int g = blockIdx.x;
  int t = threadIdx.x;
  __shared__ int s_lo, s_hi;
  if (t == 0) {
    s_lo = lower_bound_i(gid, N, g);
    s_hi = lower_bound_i(gid, N, g + 1);
  }
  __syncthreads();
  int lo = s_lo, hi = s_hi;
  float acc = 0.f;
  for (int n = lo; n < hi; ++n) acc += h[(long)n * 256 + t];
  float c = (float)(hi - lo);
  pooled[g * 256 + t] = acc / fmaxf(c, 1.f);
}

// ---------------- MLP: Dense(512,relu) -> Dense(1) fused ----------------
__global__ __launch_bounds__(256) void mlp_k(const float* __restrict__ pooled,
                                             const float* __restrict__ Wd1,
                                             const float* __restrict__ bd1,
                                             const float* __restrict__ Wd2,
                                             const float* __restrict__ bd2,
                                             float* __restrict__ outv, int G) {
  int g = blockIdx.x;
  int t = threadIdx.x;
  __shared__ float p_s[256];
  __shared__ float red[256];
  p_s[t] = pooled[g * 256 + t];
  __syncthreads();
  float acc0 = bd1[t], acc1 = bd1[t + 256];
  for (int k = 0; k < 256; ++k) {
    float pv = p_s[k];
    acc0 += pv * Wd1[k * 512 + t];
    acc1 += pv * Wd1[k * 512 + t + 256];
  }
  acc0 = fmaxf(acc0, 0.f);
  acc1 = fmaxf(acc1, 0.f);
  red[t] = acc0 * Wd2[t] + acc1 * Wd2[t + 256];
  __syncthreads();
  for (int off = 128; off > 0; off >>= 1) {
    if (t < off) red[t] += red[t + off];
    __syncthreads();
  }
  if (t == 0) outv[g] = red[0] + bd2[0];
}

extern "C" void kernel_launch(void* const* d_in, const int* in_sizes, int n_in,
                              void* d_out, int out_size, void* d_ws, size_t ws_size,
                              hipStream_t stream) {
  const float* X   = (const float*)d_in[0];
  const int*   src = (const int*)d_in[1];
  const int*   dst = (const int*)d_in[2];
  const int*   gid = (const int*)d_in[3];
  const float* W0  = (const float*)d_in[5];
  const float* al0 = (const float*)d_in[6];
  const float* ar0 = (const float*)d_in[7];
  const float* W1  = (const float*)d_in[8];
  const float* al1 = (const float*)d_in[9];
  const float* ar1 = (const float*)d_in[10];
  const float* Wd1 = (const float*)d_in[11];
  const float* bd1 = (const float*)d_in[12];
  const float* Wd2 = (const float*)d_in[13];
  const float* bd2 = (const float*)d_in[14];

  int E = in_sizes[1];
  int N = in_sizes[3];
  int G = out_size;

  float* bufA   = (float*)d_ws;                    // [N,256]
  float* bufB   = bufA + (size_t)N * 256;          // [N,256]
  float* el     = bufB + (size_t)N * 256;          // [N,8]
  float* er     = el + (size_t)N * 8;              // [N,8]
  float* pooled = er + (size_t)N * 8;              // [G,256]
  int*   ptr    = (int*)(pooled + (size_t)G * 256);  // [N+1]
  int*   cnt    = ptr + (N + 1);                   // [N]
  int*   eidx   = cnt + N;                         // [E]
  int*   bsum   = eidx + E;                        // [64]

  int nb = (N + 1023) / 1024;  // 64

  // CSR build over dst
  hipMemsetAsync(cnt, 0, (size_t)N * 4, stream);
  count_k<<<(E + 255) / 256, 256, 0, stream>>>(dst, cnt, E);
  scan1_k<<<nb, 1024, 0, stream>>>(cnt, ptr, bsum, N);
  scan2_k<<<1, 64, 0, stream>>>(bsum, nb);
  scan3_k<<<nb, 1024, 0, stream>>>(ptr, bsum, N, E);
  hipMemsetAsync(cnt, 0, (size_t)N * 4, stream);
  fill_k<<<(E + 255) / 256, 256, 0, stream>>>(dst, ptr, cnt, eidx, E);

  dim3 gg(N / 64, 4);
  // layer 0
  gemm_k<<<gg, 256, 0, stream>>>(X, W0, bufA, N, 128);
  eler_k<<<(N * 8 + 255) / 256, 256, 0, stream>>>(bufA, al0, ar0, el, er, N);
  agg_k<<<N, 256, 0, stream>>>(bufA, el, er, ptr, eidx, src, bufB, N);
  // layer 1
  gemm_k<<<gg, 256, 0, stream>>>(bufB, W1, bufA, N, 256);
  eler_k<<<(N * 8 + 255) / 256, 256, 0, stream>>>(bufA, al1, ar1, el, er, N);
  agg_k<<<N, 256, 0, stream>>>(bufA, el, er, ptr, eidx, src, bufB, N);
  // readout + MLP
  pool_k<<<G, 256, 0, stream>>>(bufB, gid, pooled, N, G);
  mlp_k<<<G, 256, 0, stream>>>(pooled, Wd1, bd1, Wd2, bd2, (float*)d_out, G);
}

// Round 3
// 776.088 us; speedup vs baseline: 1.2599x; 1.0542x over previous
//
#include <hip/hip_runtime.h>

#define LEAKY 0.2f

// ---------------- CSR build ----------------
__global__ void count_k(const int* __restrict__ dst, int* __restrict__ cnt, int E) {
  int i = blockIdx.x * blockDim.x + threadIdx.x;
  if (i < E) atomicAdd(&cnt[dst[i]], 1);
}

// hierarchical scan: 64 blocks x 1024 -> bsum[64] -> offsets
__global__ __launch_bounds__(1024) void scan1_k(const int* __restrict__ cnt,
                                                int* __restrict__ ptr,
                                                int* __restrict__ bsum, int N) {
  int t = threadIdx.x;
  int i = blockIdx.x * 1024 + t;
  int v = (i < N) ? cnt[i] : 0;
  int lane = t & 63, w = t >> 6;
  int x = v;
  #pragma unroll
  for (int off = 1; off < 64; off <<= 1) {
    int y = __shfl_up(x, off, 64);
    if (lane >= off) x += y;
  }
  __shared__ int wsum[16];
  if (lane == 63) wsum[w] = x;
  __syncthreads();
  if (t < 16) {
    int s = wsum[t];
    #pragma unroll
    for (int off = 1; off < 16; off <<= 1) {
      int y = __shfl_up(s, off, 16);
      if (t >= off) s += y;
    }
    wsum[t] = s;
  }
  __syncthreads();
  int woff = (w > 0) ? wsum[w - 1] : 0;
  int incl = x + woff;
  if (i < N) ptr[i] = incl - v;  // local exclusive
  if (t == 1023) bsum[blockIdx.x] = incl;
}

__global__ void scan2_k(int* __restrict__ bsum, int nb) {
  int t = threadIdx.x;
  int v = (t < nb) ? bsum[t] : 0;
  int x = v;
  #pragma unroll
  for (int off = 1; off < 64; off <<= 1) {
    int y = __shfl_up(x, off, 64);
    if (t >= off) x += y;
  }
  if (t < nb) bsum[t] = x - v;  // exclusive block offsets
}

__global__ __launch_bounds__(1024) void scan3_k(int* __restrict__ ptr,
                                                const int* __restrict__ bsum,
                                                int N, int E) {
  int i = blockIdx.x * 1024 + threadIdx.x;
  if (i < N) ptr[i] += bsum[blockIdx.x];
  if (i == 0) ptr[N] = E;
}

__global__ void fill_k(const int* __restrict__ dst, const int* __restrict__ ptr,
                       int* __restrict__ cur, int* __restrict__ eidx, int E) {
  int i = blockIdx.x * blockDim.x + threadIdx.x;
  if (i < E) {
    int d = dst[i];
    int p = atomicAdd(&cur[d], 1);
    eidx[ptr[d] + p] = i;
  }
}

// ---------------- GEMM: C[N][256] = A[N][K] @ B[K][256], f32 ----------------
__global__ __launch_bounds__(256) void gemm_k(const float* __restrict__ A,
                                              const float* __restrict__ B,
                                              float* __restrict__ C, int N, int K) {
  __shared__ float As[32][65];  // As[k][r], padded
  __shared__ float Bs[32][64];  // Bs[k][c]
  int t = threadIdx.x;
  int row0 = blockIdx.x * 64;
  int col0 = blockIdx.y * 64;
  int rbase = (t >> 4) * 4;
  int cbase = (t & 15) * 4;
  float acc[4][4] = {};
  for (int k0 = 0; k0 < K; k0 += 32) {
    {
      int r = t >> 2;
      #pragma unroll
      for (int it = 0; it < 2; ++it) {
        int f = (t & 3) + it * 4;
        float4 v = *(const float4*)(A + (long)(row0 + r) * K + k0 + f * 4);
        As[f * 4 + 0][r] = v.x;
        As[f * 4 + 1][r] = v.y;
        As[f * 4 + 2][r] = v.z;
        As[f * 4 + 3][r] = v.w;
      }
    }
    {
      #pragma unroll
      for (int it = 0; it < 2; ++it) {
        int kk = (t >> 4) + it * 16;
        int c = (t & 15) * 4;
        float4 v = *(const float4*)(B + (long)(k0 + kk) * 256 + col0 + c);
        *(float4*)&Bs[kk][c] = v;
      }
    }
    __syncthreads();
    #pragma unroll 8
    for (int k = 0; k < 32; ++k) {
      float4 b = *(const float4*)&Bs[k][cbase];
      float a0 = As[k][rbase + 0];
      float a1 = As[k][rbase + 1];
      float a2 = As[k][rbase + 2];
      float a3 = As[k][rbase + 3];
      acc[0][0] += a0 * b.x; acc[0][1] += a0 * b.y; acc[0][2] += a0 * b.z; acc[0][3] += a0 * b.w;
      acc[1][0] += a1 * b.x; acc[1][1] += a1 * b.y; acc[1][2] += a1 * b.z; acc[1][3] += a1 * b.w;
      acc[2][0] += a2 * b.x; acc[2][1] += a2 * b.y; acc[2][2] += a2 * b.z; acc[2][3] += a2 * b.w;
      acc[3][0] += a3 * b.x; acc[3][1] += a3 * b.y; acc[3][2] += a3 * b.z; acc[3][3] += a3 * b.w;
    }
    __syncthreads();
  }
  #pragma unroll
  for (int i = 0; i < 4; ++i) {
    float4 v = make_float4(acc[i][0], acc[i][1], acc[i][2], acc[i][3]);
    *(float4*)(C + (long)(row0 + rbase + i) * 256 + col0 + cbase) = v;
  }
}

// ---------------- el/er: per (node, head) dot with attn vectors ----------------
__global__ void eler_k(const float* __restrict__ h, const float* __restrict__ al,
                       const float* __restrict__ ar, float* __restrict__ el,
                       float* __restrict__ er, int N) {
  int i = blockIdx.x * blockDim.x + threadIdx.x;
  if (i >= N * 8) return;
  int n = i >> 3, hh = i & 7;
  const float4* hp = (const float4*)(h + (long)n * 256 + hh * 32);
  const float4* alp = (const float4*)(al + hh * 32);
  const float4* arp = (const float4*)(ar + hh * 32);
  float sl = 0.f, sr = 0.f;
  #pragma unroll
  for (int q = 0; q < 8; ++q) {
    float4 hv = hp[q], a = alp[q], b = arp[q];
    sl += hv.x * a.x + hv.y * a.y + hv.z * a.z + hv.w * a.w;
    sr += hv.x * b.x + hv.y * b.y + hv.z * b.z + hv.w * b.w;
  }
  el[i] = sl;
  er[i] = sr;
}

// ---------------- per-dst-node edge softmax + aggregate (wave-per-node) ----------------
// 4 waves/block, each wave owns one dst node. No LDS, no barriers, no atomics.
// Logit phase: lane grid = (edge-in-pass = l>>3) x (head = l&7), per-head reduction
// via __shfl_xor strides 8/16/32. Gather phase: lane l owns cols 4l..4l+3;
// attention weight broadcast from holder lane ((e&7)<<3)|(l>>3).
__global__ __launch_bounds__(256) void agg_k(const float* __restrict__ hlin,
                                             const float* __restrict__ el,
                                             const float* __restrict__ er,
                                             const int* __restrict__ ptr,
                                             const int* __restrict__ eidx,
                                             const int* __restrict__ src,
                                             float* __restrict__ out, int N) {
  int wid = threadIdx.x >> 6;
  int l = threadIdx.x & 63;
  int n = blockIdx.x * 4 + wid;
  if (n >= N) return;
  int beg = ptr[n];
  int deg = ptr[n + 1] - beg;
  float* op = out + (long)n * 256 + l * 4;
  if (deg == 0) {
    *(float4*)op = make_float4(0.f, 0.f, 0.f, 0.f);
    return;
  }
  int hh = l & 7;   // head (logit phase)
  int eo = l >> 3;  // edge offset within pass (logit phase)
  int hg = l >> 3;  // head (gather phase: col group l*4/32)
  float erv = er[(long)n * 8 + hh];
  float4 acc = make_float4(0.f, 0.f, 0.f, 0.f);

  if (deg <= 64) {
    int sid = (l < deg) ? src[eidx[beg + l]] : 0;
    int npass = (deg + 7) >> 3;
    float v[8];
    float m = -1e30f;
    #pragma unroll
    for (int p = 0; p < 8; ++p) {
      if (p < npass) {
        int e = p * 8 + eo;
        int s = __shfl(sid, e);
        float vv = -1e30f;
        if (e < deg) {
          vv = el[(long)s * 8 + hh] + erv;
          vv = vv > 0.f ? vv : LEAKY * vv;
        }
        v[p] = vv;
        m = fmaxf(m, vv);
      }
    }
    m = fmaxf(m, __shfl_xor(m, 8));
    m = fmaxf(m, __shfl_xor(m, 16));
    m = fmaxf(m, __shfl_xor(m, 32));
    float ssum = 0.f;
    #pragma unroll
    for (int p = 0; p < 8; ++p) {
      if (p < npass) {
        float ex = (p * 8 + eo < deg) ? __expf(v[p] - m) : 0.f;
        v[p] = ex;
        ssum += ex;
      }
    }
    ssum += __shfl_xor(ssum, 8);
    ssum += __shfl_xor(ssum, 16);
    ssum += __shfl_xor(ssum, 32);
    float inv = 1.0f / ssum;
    #pragma unroll
    for (int p = 0; p < 8; ++p) {
      if (p < npass) {
        v[p] *= inv;  // normalized attention, correct per-lane head
        #pragma unroll
        for (int e2 = 0; e2 < 8; ++e2) {
          int e = p * 8 + e2;
          if (e < deg) {
            float a = __shfl(v[p], (e2 << 3) | hg);
            int s = __shfl(sid, e);
            const float4 hv = *(const float4*)(hlin + (long)s * 256 + l * 4);
            acc.x += a * hv.x;
            acc.y += a * hv.y;
            acc.z += a * hv.z;
            acc.w += a * hv.w;
          }
        }
      }
    }
  } else {
    // rare slow path: recompute per sweep, no register caching
    float m = -1e30f;
    for (int base = 0; base < deg; base += 8) {
      int e = base + eo;
      float vv = -1e30f;
      if (e < deg) {
        int s = src[eidx[beg + e]];
        vv = el[(long)s * 8 + hh] + erv;
        vv = vv > 0.f ? vv : LEAKY * vv;
      }
      m = fmaxf(m, vv);
    }
    m = fmaxf(m, __shfl_xor(m, 8));
    m = fmaxf(m, __shfl_xor(m, 16));
    m = fmaxf(m, __shfl_xor(m, 32));
    float ssum = 0.f;
    for (int base = 0; base < deg; base += 8) {
      int e = base + eo;
      if (e < deg) {
        int s = src[eidx[beg + e]];
        float vv = el[(long)s * 8 + hh] + erv;
        vv = vv > 0.f ? vv : LEAKY * vv;
        ssum += __expf(vv - m);
      }
    }
    ssum += __shfl_xor(ssum, 8);
    ssum += __shfl_xor(ssum, 16);
    ssum += __shfl_xor(ssum, 32);
    float inv = 1.0f / ssum;
    for (int base = 0; base < deg; base += 8) {
      int e = base + eo;
      float a_me = 0.f;
      int s_me = 0;
      if (e < deg) {
        s_me = src[eidx[beg + e]];
        float vv = el[(long)s_me * 8 + hh] + erv;
        vv = vv > 0.f ? vv : LEAKY * vv;
        a_me = __expf(vv - m) * inv;
      }
      #pragma unroll
      for (int e2 = 0; e2 < 8; ++e2) {
        int e3 = base + e2;
        if (e3 < deg) {
          int srcl = (e2 << 3) | hg;
          float a = __shfl(a_me, srcl);
          int s = __shfl(s_me, srcl);
          const float4 hv = *(const float4*)(hlin + (long)s * 256 + l * 4);
          acc.x += a * hv.x;
          acc.y += a * hv.y;
          acc.z += a * hv.z;
          acc.w += a * hv.w;
        }
      }
    }
  }
  *(float4*)op = acc;
}

// ---------------- per-graph mean pooling (graph_ids sorted) ----------------
__device__ __forceinline__ int lower_bound_i(const int* a, int n, int key) {
  int lo = 0, hi = n;
  while (lo < hi) {
    int mid = (lo + hi) >> 1;
    if (a[mid] < key) lo = mid + 1; else hi = mid;
  }
  return lo;
}

__global__ __launch_bounds__(256) void pool_k(const float* __restrict__ h,
                                              const int* __restrict__ gid,
                                              float* __restrict__ pooled, int N, int G) {
  int g = blockIdx.x;
  int t = threadIdx.x;
  __shared__ int s_lo, s_hi;
  if (t == 0) {
    s_lo = lower_bound_i(gid, N, g);
    s_hi = lower_bound_i(gid, N, g + 1);
  }
  __syncthreads();
  int lo = s_lo, hi = s_hi;
  float acc = 0.f;
  for (int n = lo; n < hi; ++n) acc += h[(long)n * 256 + t];
  float c = (float)(hi - lo);
  pooled[g * 256 + t] = acc / fmaxf(c, 1.f);
}

// ---------------- MLP: Dense(512,relu) -> Dense(1) fused ----------------
__global__ __launch_bounds__(256) void mlp_k(const float* __restrict__ pooled,
                                             const float* __restrict__ Wd1,
                                             const float* __restrict__ bd1,
                                             const float* __restrict__ Wd2,
                                             const float* __restrict__ bd2,
                                             float* __restrict__ outv, int G) {
  int g = blockIdx.x;
  int t = threadIdx.x;
  __shared__ float p_s[256];
  __shared__ float red[256];
  p_s[t] = pooled[g * 256 + t];
  __syncthreads();
  float acc0 = bd1[t], acc1 = bd1[t + 256];
  for (int k = 0; k < 256; ++k) {
    float pv = p_s[k];
    acc0 += pv * Wd1[k * 512 + t];
    acc1 += pv * Wd1[k * 512 + t + 256];
  }
  acc0 = fmaxf(acc0, 0.f);
  acc1 = fmaxf(acc1, 0.f);
  red[t] = acc0 * Wd2[t] + acc1 * Wd2[t + 256];
  __syncthreads();
  for (int off = 128; off > 0; off >>= 1) {
    if (t < off) red[t] += red[t + off];
    __syncthreads();
  }
  if (t == 0) outv[g] = red[0] + bd2[0];
}

extern "C" void kernel_launch(void* const* d_in, const int* in_sizes, int n_in,
                              void* d_out, int out_size, void* d_ws, size_t ws_size,
                              hipStream_t stream) {
  const float* X   = (const float*)d_in[0];
  const int*   src = (const int*)d_in[1];
  const int*   dst = (const int*)d_in[2];
  const int*   gid = (const int*)d_in[3];
  const float* W0  = (const float*)d_in[5];
  const float* al0 = (const float*)d_in[6];
  const float* ar0 = (const float*)d_in[7];
  const float* W1  = (const float*)d_in[8];
  const float* al1 = (const float*)d_in[9];
  const float* ar1 = (const float*)d_in[10];
  const float* Wd1 = (const float*)d_in[11];
  const float* bd1 = (const float*)d_in[12];
  const float* Wd2 = (const float*)d_in[13];
  const float* bd2 = (const float*)d_in[14];

  int E = in_sizes[1];
  int N = in_sizes[3];
  int G = out_size;

  float* bufA   = (float*)d_ws;                    // [N,256]
  float* bufB   = bufA + (size_t)N * 256;          // [N,256]
  float* el     = bufB + (size_t)N * 256;          // [N,8]
  float* er     = el + (size_t)N * 8;              // [N,8]
  float* pooled = er + (size_t)N * 8;              // [G,256]
  int*   ptr    = (int*)(pooled + (size_t)G * 256);  // [N+1]
  int*   cnt    = ptr + (N + 1);                   // [N]
  int*   eidx   = cnt + N;                         // [E]
  int*   bsum   = eidx + E;                        // [64]

  int nb = (N + 1023) / 1024;  // 64

  // CSR build over dst
  hipMemsetAsync(cnt, 0, (size_t)N * 4, stream);
  count_k<<<(E + 255) / 256, 256, 0, stream>>>(dst, cnt, E);
  scan1_k<<<nb, 1024, 0, stream>>>(cnt, ptr, bsum, N);
  scan2_k<<<1, 64, 0, stream>>>(bsum, nb);
  scan3_k<<<nb, 1024, 0, stream>>>(ptr, bsum, N, E);
  hipMemsetAsync(cnt, 0, (size_t)N * 4, stream);
  fill_k<<<(E + 255) / 256, 256, 0, stream>>>(dst, ptr, cnt, eidx, E);

  dim3 gg(N / 64, 4);
  // layer 0
  gemm_k<<<gg, 256, 0, stream>>>(X, W0, bufA, N, 128);
  eler_k<<<(N * 8 + 255) / 256, 256, 0, stream>>>(bufA, al0, ar0, el, er, N);
  agg_k<<<(N + 3) / 4, 256, 0, stream>>>(bufA, el, er, ptr, eidx, src, bufB, N);
  // layer 1
  gemm_k<<<gg, 256, 0, stream>>>(bufB, W1, bufA, N, 256);
  eler_k<<<(N * 8 + 255) / 256, 256, 0, stream>>>(bufA, al1, ar1, el, er, N);
  agg_k<<<(N + 3) / 4, 256, 0, stream>>>(bufA, el, er, ptr, eidx, src, bufB, N);
  // readout + MLP
  pool_k<<<G, 256, 0, stream>>>(bufB, gid, pooled, N, G);
  mlp_k<<<G, 256, 0, stream>>>(pooled, Wd1, bd1, Wd2, bd2, (float*)d_out, G);
}

// Round 4
// 723.602 us; speedup vs baseline: 1.3513x; 1.0725x over previous
//
#include <hip/hip_runtime.h>

#define LEAKY 0.2f

__device__ __forceinline__ unsigned short f2bf(float f) {
  unsigned u = __float_as_uint(f);
  unsigned r = (u + 0x7fff + ((u >> 16) & 1)) >> 16;  // round-to-nearest-even
  return (unsigned short)r;
}
__device__ __forceinline__ float bf2f(unsigned short u) {
  return __uint_as_float(((unsigned)u) << 16);
}

// ---------------- CSR build ----------------
__global__ void count_k(const int* __restrict__ dst, int* __restrict__ cnt, int E) {
  int i = blockIdx.x * blockDim.x + threadIdx.x;
  if (i < E) atomicAdd(&cnt[dst[i]], 1);
}

__global__ __launch_bounds__(1024) void scan1_k(const int* __restrict__ cnt,
                                                int* __restrict__ ptr,
                                                int* __restrict__ bsum, int N) {
  int t = threadIdx.x;
  int i = blockIdx.x * 1024 + t;
  int v = (i < N) ? cnt[i] : 0;
  int lane = t & 63, w = t >> 6;
  int x = v;
  #pragma unroll
  for (int off = 1; off < 64; off <<= 1) {
    int y = __shfl_up(x, off, 64);
    if (lane >= off) x += y;
  }
  __shared__ int wsum[16];
  if (lane == 63) wsum[w] = x;
  __syncthreads();
  if (t < 16) {
    int s = wsum[t];
    #pragma unroll
    for (int off = 1; off < 16; off <<= 1) {
      int y = __shfl_up(s, off, 16);
      if (t >= off) s += y;
    }
    wsum[t] = s;
  }
  __syncthreads();
  int woff = (w > 0) ? wsum[w - 1] : 0;
  int incl = x + woff;
  if (i < N) ptr[i] = incl - v;  // local exclusive
  if (t == 1023) bsum[blockIdx.x] = incl;
}

__global__ void scan2_k(int* __restrict__ bsum, int nb) {
  int t = threadIdx.x;
  int v = (t < nb) ? bsum[t] : 0;
  int x = v;
  #pragma unroll
  for (int off = 1; off < 64; off <<= 1) {
    int y = __shfl_up(x, off, 64);
    if (t >= off) x += y;
  }
  if (t < nb) bsum[t] = x - v;
}

__global__ __launch_bounds__(1024) void scan3_k(int* __restrict__ ptr,
                                                const int* __restrict__ bsum,
                                                int N, int E) {
  int i = blockIdx.x * 1024 + threadIdx.x;
  if (i < N) ptr[i] += bsum[blockIdx.x];
  if (i == 0) ptr[N] = E;
}

__global__ void fill_k(const int* __restrict__ dst, const int* __restrict__ ptr,
                       int* __restrict__ cur, int* __restrict__ eidx, int E) {
  int i = blockIdx.x * blockDim.x + threadIdx.x;
  if (i < E) {
    int d = dst[i];
    int p = atomicAdd(&cur[d], 1);
    eidx[ptr[d] + p] = i;
  }
}

// ---------------- GEMM: C[N][256] = A[N][K] @ B[K][256], f32; optional bf16 copy ----------------
__global__ __launch_bounds__(256) void gemm_k(const float* __restrict__ A,
                                              const float* __restrict__ B,
                                              float* __restrict__ C,
                                              unsigned short* __restrict__ Cb,
                                              int N, int K) {
  __shared__ float As[32][65];
  __shared__ float Bs[32][64];
  int t = threadIdx.x;
  int row0 = blockIdx.x * 64;
  int col0 = blockIdx.y * 64;
  int rbase = (t >> 4) * 4;
  int cbase = (t & 15) * 4;
  float acc[4][4] = {};
  for (int k0 = 0; k0 < K; k0 += 32) {
    {
      int r = t >> 2;
      #pragma unroll
      for (int it = 0; it < 2; ++it) {
        int f = (t & 3) + it * 4;
        float4 v = *(const float4*)(A + (long)(row0 + r) * K + k0 + f * 4);
        As[f * 4 + 0][r] = v.x;
        As[f * 4 + 1][r] = v.y;
        As[f * 4 + 2][r] = v.z;
        As[f * 4 + 3][r] = v.w;
      }
    }
    {
      #pragma unroll
      for (int it = 0; it < 2; ++it) {
        int kk = (t >> 4) + it * 16;
        int c = (t & 15) * 4;
        float4 v = *(const float4*)(B + (long)(k0 + kk) * 256 + col0 + c);
        *(float4*)&Bs[kk][c] = v;
      }
    }
    __syncthreads();
    #pragma unroll 8
    for (int k = 0; k < 32; ++k) {
      float4 b = *(const float4*)&Bs[k][cbase];
      float a0 = As[k][rbase + 0];
      float a1 = As[k][rbase + 1];
      float a2 = As[k][rbase + 2];
      float a3 = As[k][rbase + 3];
      acc[0][0] += a0 * b.x; acc[0][1] += a0 * b.y; acc[0][2] += a0 * b.z; acc[0][3] += a0 * b.w;
      acc[1][0] += a1 * b.x; acc[1][1] += a1 * b.y; acc[1][2] += a1 * b.z; acc[1][3] += a1 * b.w;
      acc[2][0] += a2 * b.x; acc[2][1] += a2 * b.y; acc[2][2] += a2 * b.z; acc[2][3] += a2 * b.w;
      acc[3][0] += a3 * b.x; acc[3][1] += a3 * b.y; acc[3][2] += a3 * b.z; acc[3][3] += a3 * b.w;
    }
    __syncthreads();
  }
  #pragma unroll
  for (int i = 0; i < 4; ++i) {
    float4 v = make_float4(acc[i][0], acc[i][1], acc[i][2], acc[i][3]);
    long off = (long)(row0 + rbase + i) * 256 + col0 + cbase;
    *(float4*)(C + off) = v;
    if (Cb) {
      ushort4 u = make_ushort4(f2bf(v.x), f2bf(v.y), f2bf(v.z), f2bf(v.w));
      *(ushort4*)(Cb + off) = u;
    }
  }
}

// ---------------- el/er ----------------
__global__ void eler_k(const float* __restrict__ h, const float* __restrict__ al,
                       const float* __restrict__ ar, float* __restrict__ el,
                       float* __restrict__ er, int N) {
  int i = blockIdx.x * blockDim.x + threadIdx.x;
  if (i >= N * 8) return;
  int n = i >> 3, hh = i & 7;
  const float4* hp = (const float4*)(h + (long)n * 256 + hh * 32);
  const float4* alp = (const float4*)(al + hh * 32);
  const float4* arp = (const float4*)(ar + hh * 32);
  float sl = 0.f, sr = 0.f;
  #pragma unroll
  for (int q = 0; q < 8; ++q) {
    float4 hv = hp[q], a = alp[q], b = arp[q];
    sl += hv.x * a.x + hv.y * a.y + hv.z * a.z + hv.w * a.w;
    sr += hv.x * b.x + hv.y * b.y + hv.z * b.z + hv.w * b.w;
  }
  el[i] = sl;
  er[i] = sr;
}

// ---------------- agg (f32 gather), wave-per-node ----------------
__global__ __launch_bounds__(256) void agg_k(const float* __restrict__ hlin,
                                             const float* __restrict__ el,
                                             const float* __restrict__ er,
                                             const int* __restrict__ ptr,
                                             const int* __restrict__ eidx,
                                             const int* __restrict__ src,
                                             float* __restrict__ out, int N) {
  int wid = threadIdx.x >> 6;
  int l = threadIdx.x & 63;
  int n = blockIdx.x * 4 + wid;
  if (n >= N) return;
  int beg = ptr[n];
  int deg = ptr[n + 1] - beg;
  float* op = out + (long)n * 256 + l * 4;
  if (deg == 0) {
    *(float4*)op = make_float4(0.f, 0.f, 0.f, 0.f);
    return;
  }
  int hh = l & 7;
  int eo = l >> 3;
  int hg = l >> 3;
  float erv = er[(long)n * 8 + hh];
  float4 acc = make_float4(0.f, 0.f, 0.f, 0.f);

  if (deg <= 64) {
    int sid = (l < deg) ? src[eidx[beg + l]] : 0;
    int npass = (deg + 7) >> 3;
    float v[8];
    float m = -1e30f;
    #pragma unroll
    for (int p = 0; p < 8; ++p) {
      if (p < npass) {
        int e = p * 8 + eo;
        int s = __shfl(sid, e);
        float vv = -1e30f;
        if (e < deg) {
          vv = el[(long)s * 8 + hh] + erv;
          vv = vv > 0.f ? vv : LEAKY * vv;
        }
        v[p] = vv;
        m = fmaxf(m, vv);
      }
    }
    m = fmaxf(m, __shfl_xor(m, 8));
    m = fmaxf(m, __shfl_xor(m, 16));
    m = fmaxf(m, __shfl_xor(m, 32));
    float ssum = 0.f;
    #pragma unroll
    for (int p = 0; p < 8; ++p) {
      if (p < npass) {
        float ex = (p * 8 + eo < deg) ? __expf(v[p] - m) : 0.f;
        v[p] = ex;
        ssum += ex;
      }
    }
    ssum += __shfl_xor(ssum, 8);
    ssum += __shfl_xor(ssum, 16);
    ssum += __shfl_xor(ssum, 32);
    float inv = 1.0f / ssum;
    #pragma unroll
    for (int p = 0; p < 8; ++p) {
      if (p < npass) {
        v[p] *= inv;
        #pragma unroll
        for (int e2 = 0; e2 < 8; ++e2) {
          int e = p * 8 + e2;
          if (e < deg) {
            float a = __shfl(v[p], (e2 << 3) | hg);
            int s = __shfl(sid, e);
            const float4 hv = *(const float4*)(hlin + (long)s * 256 + l * 4);
            acc.x += a * hv.x;
            acc.y += a * hv.y;
            acc.z += a * hv.z;
            acc.w += a * hv.w;
          }
        }
      }
    }
  } else {
    float m = -1e30f;
    for (int base = 0; base < deg; base += 8) {
      int e = base + eo;
      float vv = -1e30f;
      if (e < deg) {
        int s = src[eidx[beg + e]];
        vv = el[(long)s * 8 + hh] + erv;
        vv = vv > 0.f ? vv : LEAKY * vv;
      }
      m = fmaxf(m, vv);
    }
    m = fmaxf(m, __shfl_xor(m, 8));
    m = fmaxf(m, __shfl_xor(m, 16));
    m = fmaxf(m, __shfl_xor(m, 32));
    float ssum = 0.f;
    for (int base = 0; base < deg; base += 8) {
      int e = base + eo;
      if (e < deg) {
        int s = src[eidx[beg + e]];
        float vv = el[(long)s * 8 + hh] + erv;
        vv = vv > 0.f ? vv : LEAKY * vv;
        ssum += __expf(vv - m);
      }
    }
    ssum += __shfl_xor(ssum, 8);
    ssum += __shfl_xor(ssum, 16);
    ssum += __shfl_xor(ssum, 32);
    float inv = 1.0f / ssum;
    for (int base = 0; base < deg; base += 8) {
      int e = base + eo;
      float a_me = 0.f;
      int s_me = 0;
      if (e < deg) {
        s_me = src[eidx[beg + e]];
        float vv = el[(long)s_me * 8 + hh] + erv;
        vv = vv > 0.f ? vv : LEAKY * vv;
        a_me = __expf(vv - m) * inv;
      }
      #pragma unroll
      for (int e2 = 0; e2 < 8; ++e2) {
        int e3 = base + e2;
        if (e3 < deg) {
          int srcl = (e2 << 3) | hg;
          float a = __shfl(a_me, srcl);
          int s = __shfl(s_me, srcl);
          const float4 hv = *(const float4*)(hlin + (long)s * 256 + l * 4);
          acc.x += a * hv.x;
          acc.y += a * hv.y;
          acc.z += a * hv.z;
          acc.w += a * hv.w;
        }
      }
    }
  }
  *(float4*)op = acc;
}

// ---------------- agg with bf16 gather (512B rows), wave-per-node ----------------
__global__ __launch_bounds__(256) void agg1bf_k(const unsigned short* __restrict__ hb,
                                                const float* __restrict__ el,
                                                const float* __restrict__ er,
                                                const int* __restrict__ ptr,
                                                const int* __restrict__ eidx,
                                                const int* __restrict__ src,
                                                float* __restrict__ out, int N) {
  int wid = threadIdx.x >> 6;
  int l = threadIdx.x & 63;
  int n = blockIdx.x * 4 + wid;
  if (n >= N) return;
  int beg = ptr[n];
  int deg = ptr[n + 1] - beg;
  float* op = out + (long)n * 256 + l * 4;
  if (deg == 0) {
    *(float4*)op = make_float4(0.f, 0.f, 0.f, 0.f);
    return;
  }
  int hh = l & 7;
  int eo = l >> 3;
  int hg = l >> 3;
  float erv = er[(long)n * 8 + hh];
  float4 acc = make_float4(0.f, 0.f, 0.f, 0.f);

  if (deg <= 64) {
    int sid = (l < deg) ? src[eidx[beg + l]] : 0;
    int npass = (deg + 7) >> 3;
    float v[8];
    float m = -1e30f;
    #pragma unroll
    for (int p = 0; p < 8; ++p) {
      if (p < npass) {
        int e = p * 8 + eo;
        int s = __shfl(sid, e);
        float vv = -1e30f;
        if (e < deg) {
          vv = el[(long)s * 8 + hh] + erv;
          vv = vv > 0.f ? vv : LEAKY * vv;
        }
        v[p] = vv;
        m = fmaxf(m, vv);
      }
    }
    m = fmaxf(m, __shfl_xor(m, 8));
    m = fmaxf(m, __shfl_xor(m, 16));
    m = fmaxf(m, __shfl_xor(m, 32));
    float ssum = 0.f;
    #pragma unroll
    for (int p = 0; p < 8; ++p) {
      if (p < npass) {
        float ex = (p * 8 + eo < deg) ? __expf(v[p] - m) : 0.f;
        v[p] = ex;
        ssum += ex;
      }
    }
    ssum += __shfl_xor(ssum, 8);
    ssum += __shfl_xor(ssum, 16);
    ssum += __shfl_xor(ssum, 32);
    float inv = 1.0f / ssum;
    #pragma unroll
    for (int p = 0; p < 8; ++p) {
      if (p < npass) {
        v[p] *= inv;
        #pragma unroll
        for (int e2 = 0; e2 < 8; ++e2) {
          int e = p * 8 + e2;
          if (e < deg) {
            float a = __shfl(v[p], (e2 << 3) | hg);
            int s = __shfl(sid, e);
            const ushort4 hv = *(const ushort4*)(hb + (long)s * 256 + l * 4);
            acc.x += a * bf2f(hv.x);
            acc.y += a * bf2f(hv.y);
            acc.z += a * bf2f(hv.z);
            acc.w += a * bf2f(hv.w);
          }
        }
      }
    }
  } else {
    float m = -1e30f;
    for (int base = 0; base < deg; base += 8) {
      int e = base + eo;
      float vv = -1e30f;
      if (e < deg) {
        int s = src[eidx[beg + e]];
        vv = el[(long)s * 8 + hh] + erv;
        vv = vv > 0.f ? vv : LEAKY * vv;
      }
      m = fmaxf(m, vv);
    }
    m = fmaxf(m, __shfl_xor(m, 8));
    m = fmaxf(m, __shfl_xor(m, 16));
    m = fmaxf(m, __shfl_xor(m, 32));
    float ssum = 0.f;
    for (int base = 0; base < deg; base += 8) {
      int e = base + eo;
      if (e < deg) {
        int s = src[eidx[beg + e]];
        float vv = el[(long)s * 8 + hh] + erv;
        vv = vv > 0.f ? vv : LEAKY * vv;
        ssum += __expf(vv - m);
      }
    }
    ssum += __shfl_xor(ssum, 8);
    ssum += __shfl_xor(ssum, 16);
    ssum += __shfl_xor(ssum, 32);
    float inv = 1.0f / ssum;
    for (int base = 0; base < deg; base += 8) {
      int e = base + eo;
      float a_me = 0.f;
      int s_me = 0;
      if (e < deg) {
        s_me = src[eidx[beg + e]];
        float vv = el[(long)s_me * 8 + hh] + erv;
        vv = vv > 0.f ? vv : LEAKY * vv;
        a_me = __expf(vv - m) * inv;
      }
      #pragma unroll
      for (int e2 = 0; e2 < 8; ++e2) {
        int e3 = base + e2;
        if (e3 < deg) {
          int srcl = (e2 << 3) | hg;
          float a = __shfl(a_me, srcl);
          int s = __shfl(s_me, srcl);
          const ushort4 hv = *(const ushort4*)(hb + (long)s * 256 + l * 4);
          acc.x += a * bf2f(hv.x);
          acc.y += a * bf2f(hv.y);
          acc.z += a * bf2f(hv.z);
          acc.w += a * bf2f(hv.w);
        }
      }
    }
  }
  *(float4*)op = acc;
}

// ---------------- per-graph mean pooling ----------------
__device__ __forceinline__ int lower_bound_i(const int* a, int n, int key) {
  int lo = 0, hi = n;
  while (lo < hi) {
    int mid = (lo + hi) >> 1;
    if (a[mid] < key) lo = mid + 1; else hi = mid;
  }
  return lo;
}

__global__ __launch_bounds__(256) void pool_k(const float* __restrict__ h,
                                              const int* __restrict__ gid,
                                              float* __restrict__ pooled, int N, int G) {
  int g = blockIdx.x;
  int t = threadIdx.x;
  __shared__ int s_lo, s_hi;
  if (t == 0) {
    s_lo = lower_bound_i(gid, N, g);
    s_hi = lower_bound_i(gid, N, g + 1);
  }
  __syncthreads();
  int lo = s_lo, hi = s_hi;
  float acc = 0.f;
  for (int n = lo; n < hi; ++n) acc += h[(long)n * 256 + t];
  float c = (float)(hi - lo);
  pooled[g * 256 + t] = acc / fmaxf(c, 1.f);
}

// ---------------- MLP ----------------
__global__ __launch_bounds__(256) void mlp_k(const float* __restrict__ pooled,
                                             const float* __restrict__ Wd1,
                                             const float* __restrict__ bd1,
                                             const float* __restrict__ Wd2,
                                             const float* __restrict__ bd2,
                                             float* __restrict__ outv, int G) {
  int g = blockIdx.x;
  int t = threadIdx.x;
  __shared__ float p_s[256];
  __shared__ float red[256];
  p_s[t] = pooled[g * 256 + t];
  __syncthreads();
  float acc0 = bd1[t], acc1 = bd1[t + 256];
  for (int k = 0; k < 256; ++k) {
    float pv = p_s[k];
    acc0 += pv * Wd1[k * 512 + t];
    acc1 += pv * Wd1[k * 512 + t + 256];
  }
  acc0 = fmaxf(acc0, 0.f);
  acc1 = fmaxf(acc1, 0.f);
  red[t] = acc0 * Wd2[t] + acc1 * Wd2[t + 256];
  __syncthreads();
  for (int off = 128; off > 0; off >>= 1) {
    if (t < off) red[t] += red[t + off];
    __syncthreads();
  }
  if (t == 0) outv[g] = red[0] + bd2[0];
}

extern "C" void kernel_launch(void* const* d_in, const int* in_sizes, int n_in,
                              void* d_out, int out_size, void* d_ws, size_t ws_size,
                              hipStream_t stream) {
  const float* X   = (const float*)d_in[0];
  const int*   src = (const int*)d_in[1];
  const int*   dst = (const int*)d_in[2];
  const int*   gid = (const int*)d_in[3];
  const float* W0  = (const float*)d_in[5];
  const float* al0 = (const float*)d_in[6];
  const float* ar0 = (const float*)d_in[7];
  const float* W1  = (const float*)d_in[8];
  const float* al1 = (const float*)d_in[9];
  const float* ar1 = (const float*)d_in[10];
  const float* Wd1 = (const float*)d_in[11];
  const float* bd1 = (const float*)d_in[12];
  const float* Wd2 = (const float*)d_in[13];
  const float* bd2 = (const float*)d_in[14];

  int E = in_sizes[1];
  int N = in_sizes[3];
  int G = out_size;

  float* h0     = (float*)d_ws;                    // [N,256]; reused as h1 after agg0
  float* bAgg   = h0 + (size_t)N * 256;            // [N,256] agg out; reused as final h
  float* el     = bAgg + (size_t)N * 256;          // [N,8]
  float* er     = el + (size_t)N * 8;              // [N,8]
  float* pooled = er + (size_t)N * 8;              // [G,256]
  int*   ptr    = (int*)(pooled + (size_t)G * 256);  // [N+1]
  int*   cnt    = ptr + (N + 1);                   // [N]
  int*   eidx   = cnt + N;                         // [E]
  int*   bsum   = eidx + E;                        // [64]
  unsigned short* h1b = (unsigned short*)(bsum + 64);  // [N,256] bf16
  size_t needed = (size_t)((char*)(h1b + (size_t)N * 256) - (char*)d_ws);
  bool use_bf = (ws_size >= needed);

  int nb = (N + 1023) / 1024;

  // CSR build over dst
  hipMemsetAsync(cnt, 0, (size_t)N * 4, stream);
  count_k<<<(E + 255) / 256, 256, 0, stream>>>(dst, cnt, E);
  scan1_k<<<nb, 1024, 0, stream>>>(cnt, ptr, bsum, N);
  scan2_k<<<1, 64, 0, stream>>>(bsum, nb);
  scan3_k<<<nb, 1024, 0, stream>>>(ptr, bsum, N, E);
  hipMemsetAsync(cnt, 0, (size_t)N * 4, stream);
  fill_k<<<(E + 255) / 256, 256, 0, stream>>>(dst, ptr, cnt, eidx, E);

  dim3 gg(N / 64, 4);
  // layer 0 (exact f32)
  gemm_k<<<gg, 256, 0, stream>>>(X, W0, h0, (unsigned short*)nullptr, N, 128);
  eler_k<<<(N * 8 + 255) / 256, 256, 0, stream>>>(h0, al0, ar0, el, er, N);
  agg_k<<<(N + 3) / 4, 256, 0, stream>>>(h0, el, er, ptr, eidx, src, bAgg, N);
  // layer 1 (bf16 message gather)
  gemm_k<<<gg, 256, 0, stream>>>(bAgg, W1, h0, use_bf ? h1b : (unsigned short*)nullptr, N, 256);
  eler_k<<<(N * 8 + 255) / 256, 256, 0, stream>>>(h0, al1, ar1, el, er, N);
  if (use_bf) {
    agg1bf_k<<<(N + 3) / 4, 256, 0, stream>>>(h1b, el, er, ptr, eidx, src, bAgg, N);
  } else {
    agg_k<<<(N + 3) / 4, 256, 0, stream>>>(h0, el, er, ptr, eidx, src, bAgg, N);
  }
  // readout + MLP
  pool_k<<<G, 256, 0, stream>>>(bAgg, gid, pooled, N, G);
  mlp_k<<<G, 256, 0, stream>>>(pooled, Wd1, bd1, Wd2, bd2, (float*)d_out, G);
}

// Round 5
// 531.002 us; speedup vs baseline: 1.8414x; 1.3627x over previous
//
#include <hip/hip_runtime.h>

#define LEAKY 0.2f

typedef unsigned short ushort_t;
typedef __attribute__((ext_vector_type(8))) short short8;
typedef __attribute__((ext_vector_type(4))) float f32x4;

__device__ __forceinline__ unsigned short f2bf(float f) {
  unsigned u = __float_as_uint(f);
  unsigned r = (u + 0x7fff + ((u >> 16) & 1)) >> 16;  // RNE
  return (unsigned short)r;
}
__device__ __forceinline__ float bf2f(unsigned short u) {
  return __uint_as_float(((unsigned)u) << 16);
}

// ---------------- CSR build ----------------
__global__ void count_k(const int* __restrict__ dst, int* __restrict__ cnt, int E) {
  int i = blockIdx.x * blockDim.x + threadIdx.x;
  if (i < E) atomicAdd(&cnt[dst[i]], 1);
}

__global__ __launch_bounds__(1024) void scan1_k(const int* __restrict__ cnt,
                                                int* __restrict__ ptr,
                                                int* __restrict__ bsum, int N) {
  int t = threadIdx.x;
  int i = blockIdx.x * 1024 + t;
  int v = (i < N) ? cnt[i] : 0;
  int lane = t & 63, w = t >> 6;
  int x = v;
  #pragma unroll
  for (int off = 1; off < 64; off <<= 1) {
    int y = __shfl_up(x, off, 64);
    if (lane >= off) x += y;
  }
  __shared__ int wsum[16];
  if (lane == 63) wsum[w] = x;
  __syncthreads();
  if (t < 16) {
    int s = wsum[t];
    #pragma unroll
    for (int off = 1; off < 16; off <<= 1) {
      int y = __shfl_up(s, off, 16);
      if (t >= off) s += y;
    }
    wsum[t] = s;
  }
  __syncthreads();
  int woff = (w > 0) ? wsum[w - 1] : 0;
  int incl = x + woff;
  if (i < N) ptr[i] = incl - v;
  if (t == 1023) bsum[blockIdx.x] = incl;
}

__global__ void scan2_k(int* __restrict__ bsum, int nb) {
  int t = threadIdx.x;
  int v = (t < nb) ? bsum[t] : 0;
  int x = v;
  #pragma unroll
  for (int off = 1; off < 64; off <<= 1) {
    int y = __shfl_up(x, off, 64);
    if (t >= off) x += y;
  }
  if (t < nb) bsum[t] = x - v;
}

__global__ __launch_bounds__(1024) void scan3_k(int* __restrict__ ptr,
                                                const int* __restrict__ bsum,
                                                int N, int E) {
  int i = blockIdx.x * 1024 + threadIdx.x;
  if (i < N) ptr[i] += bsum[blockIdx.x];
  if (i == 0) ptr[N] = E;
}

__global__ void fill_k(const int* __restrict__ dst, const int* __restrict__ ptr,
                       int* __restrict__ cur, int* __restrict__ eidx, int E) {
  int i = blockIdx.x * blockDim.x + threadIdx.x;
  if (i < E) {
    int d = dst[i];
    int p = atomicAdd(&cur[d], 1);
    eidx[ptr[d] + p] = i;
  }
}

// ---------------- W split+transpose: W[K][256] -> Wh/Wl[256][K] bf16 ----------------
__global__ void wsplit_k(const float* __restrict__ W, ushort_t* __restrict__ Wh,
                         ushort_t* __restrict__ Wl, int K) {
  int i = blockIdx.x * 256 + threadIdx.x;
  if (i >= 256 * K) return;
  int k = i % K, c = i / K;
  float x = W[(long)k * 256 + c];
  unsigned short hi = f2bf(x);
  Wh[i] = hi;
  Wl[i] = f2bf(x - bf2f(hi));
}

// ---------------- MFMA GEMM: C_bf16[N][256] = A_f32[N][K] @ W (hi/lo split) ----------------
// 128x64 tile, 4 waves (wave w: rows w*32..w*32+31), 16x16x32 bf16 MFMA.
// 3-pass split: Ahi*Bhi + Alo*Bhi + Ahi*Blo  (~f32 accuracy).
#define LDT 40  // padded LDS stride (bf16 elems): 80B, 16B-aligned, 2-way banks
__global__ __launch_bounds__(256) void gemm_bf_k(const float* __restrict__ A,
                                                 const ushort_t* __restrict__ Bh,
                                                 const ushort_t* __restrict__ Bl,
                                                 ushort_t* __restrict__ C,
                                                 int N, int K) {
  __shared__ ushort_t Ah[128 * LDT];
  __shared__ ushort_t Al[128 * LDT];
  __shared__ ushort_t Bth[64 * LDT];
  __shared__ ushort_t Btl[64 * LDT];
  int t = threadIdx.x;
  int w = t >> 6, l = t & 63;
  long row0 = (long)blockIdx.x * 128;
  int col0 = blockIdx.y * 64;
  int fr = l & 15;          // frag row (A) / col (B,C)
  int ko = (l >> 4) * 8;    // frag k offset
  int ar = t >> 3;          // staging: A row 0..31 (+i*32)
  int ak = (t & 7) * 4;     // staging: A k 0..28
  int bc = t >> 2;          // staging: B col 0..63
  int bk = (t & 3) * 8;     // staging: B k 0,8,16,24
  f32x4 acc[2][4] = {};

  for (int k0 = 0; k0 < K; k0 += 32) {
    float4 av[4];
    #pragma unroll
    for (int i = 0; i < 4; ++i)
      av[i] = *(const float4*)(A + (row0 + ar + i * 32) * K + k0 + ak);
    uint4 bhv = *(const uint4*)(Bh + (long)(col0 + bc) * K + k0 + bk);
    uint4 blv = *(const uint4*)(Bl + (long)(col0 + bc) * K + k0 + bk);
    __syncthreads();
    #pragma unroll
    for (int i = 0; i < 4; ++i) {
      float xs[4] = {av[i].x, av[i].y, av[i].z, av[i].w};
      ushort4 hi, lo;
      unsigned short h0 = f2bf(xs[0]); unsigned short l0 = f2bf(xs[0] - bf2f(h0));
      unsigned short h1 = f2bf(xs[1]); unsigned short l1 = f2bf(xs[1] - bf2f(h1));
      unsigned short h2 = f2bf(xs[2]); unsigned short l2 = f2bf(xs[2] - bf2f(h2));
      unsigned short h3 = f2bf(xs[3]); unsigned short l3 = f2bf(xs[3] - bf2f(h3));
      hi = make_ushort4(h0, h1, h2, h3);
      lo = make_ushort4(l0, l1, l2, l3);
      *(ushort4*)&Ah[(ar + i * 32) * LDT + ak] = hi;
      *(ushort4*)&Al[(ar + i * 32) * LDT + ak] = lo;
    }
    *(uint4*)&Bth[bc * LDT + bk] = bhv;
    *(uint4*)&Btl[bc * LDT + bk] = blv;
    __syncthreads();
    short8 fah[2], fal[2], fbh[4], fbl[4];
    #pragma unroll
    for (int m = 0; m < 2; ++m) {
      fah[m] = *(const short8*)&Ah[(w * 32 + m * 16 + fr) * LDT + ko];
      fal[m] = *(const short8*)&Al[(w * 32 + m * 16 + fr) * LDT + ko];
    }
    #pragma unroll
    for (int n = 0; n < 4; ++n) {
      fbh[n] = *(const short8*)&Bth[(n * 16 + fr) * LDT + ko];
      fbl[n] = *(const short8*)&Btl[(n * 16 + fr) * LDT + ko];
    }
    #pragma unroll
    for (int m = 0; m < 2; ++m) {
      #pragma unroll
      for (int n = 0; n < 4; ++n) {
        acc[m][n] = __builtin_amdgcn_mfma_f32_16x16x32_bf16(fah[m], fbh[n], acc[m][n], 0, 0, 0);
        acc[m][n] = __builtin_amdgcn_mfma_f32_16x16x32_bf16(fal[m], fbh[n], acc[m][n], 0, 0, 0);
        acc[m][n] = __builtin_amdgcn_mfma_f32_16x16x32_bf16(fah[m], fbl[n], acc[m][n], 0, 0, 0);
      }
    }
  }
  int crow = (l >> 4) * 4;
  #pragma unroll
  for (int m = 0; m < 2; ++m) {
    #pragma unroll
    for (int n = 0; n < 4; ++n) {
      #pragma unroll
      for (int r = 0; r < 4; ++r) {
        long row = row0 + w * 32 + m * 16 + crow + r;
        int col = col0 + n * 16 + fr;
        C[row * 256 + col] = f2bf(acc[m][n][r]);
      }
    }
  }
}

// ---------------- el/er from bf16 h ----------------
__global__ void eler_k(const ushort_t* __restrict__ h, const float* __restrict__ al,
                       const float* __restrict__ ar, float* __restrict__ el,
                       float* __restrict__ er, int N) {
  int i = blockIdx.x * blockDim.x + threadIdx.x;
  if (i >= N * 8) return;
  int n = i >> 3, hh = i & 7;
  const ushort_t* hp = h + (long)n * 256 + hh * 32;
  const float* alp = al + hh * 32;
  const float* arp = ar + hh * 32;
  float sl = 0.f, sr = 0.f;
  #pragma unroll
  for (int q = 0; q < 4; ++q) {
    uint4 v = *(const uint4*)(hp + q * 8);
    unsigned vv[4] = {v.x, v.y, v.z, v.w};
    #pragma unroll
    for (int j = 0; j < 4; ++j) {
      float f0 = bf2f((unsigned short)(vv[j] & 0xffff));
      float f1 = bf2f((unsigned short)(vv[j] >> 16));
      int d = q * 8 + j * 2;
      sl += f0 * alp[d] + f1 * alp[d + 1];
      sr += f0 * arp[d] + f1 * arp[d + 1];
    }
  }
  el[i] = sl;
  er[i] = sr;
}

// ---------------- agg: bf16 gather, wave-per-node ----------------
__global__ __launch_bounds__(256) void agg_bf_k(const ushort_t* __restrict__ hb,
                                                const float* __restrict__ el,
                                                const float* __restrict__ er,
                                                const int* __restrict__ ptr,
                                                const int* __restrict__ eidx,
                                                const int* __restrict__ src,
                                                float* __restrict__ out, int N) {
  int wid = threadIdx.x >> 6;
  int l = threadIdx.x & 63;
  int n = blockIdx.x * 4 + wid;
  if (n >= N) return;
  int beg = ptr[n];
  int deg = ptr[n + 1] - beg;
  float* op = out + (long)n * 256 + l * 4;
  if (deg == 0) {
    *(float4*)op = make_float4(0.f, 0.f, 0.f, 0.f);
    return;
  }
  int hh = l & 7;
  int eo = l >> 3;
  int hg = l >> 3;
  float erv = er[(long)n * 8 + hh];
  float4 acc = make_float4(0.f, 0.f, 0.f, 0.f);

  if (deg <= 64) {
    int sid = (l < deg) ? src[eidx[beg + l]] : 0;
    int npass = (deg + 7) >> 3;
    float v[8];
    float m = -1e30f;
    #pragma unroll
    for (int p = 0; p < 8; ++p) {
      if (p < npass) {
        int e = p * 8 + eo;
        int s = __shfl(sid, e);
        float vv = -1e30f;
        if (e < deg) {
          vv = el[(long)s * 8 + hh] + erv;
          vv = vv > 0.f ? vv : LEAKY * vv;
        }
        v[p] = vv;
        m = fmaxf(m, vv);
      }
    }
    m = fmaxf(m, __shfl_xor(m, 8));
    m = fmaxf(m, __shfl_xor(m, 16));
    m = fmaxf(m, __shfl_xor(m, 32));
    float ssum = 0.f;
    #pragma unroll
    for (int p = 0; p < 8; ++p) {
      if (p < npass) {
        float ex = (p * 8 + eo < deg) ? __expf(v[p] - m) : 0.f;
        v[p] = ex;
        ssum += ex;
      }
    }
    ssum += __shfl_xor(ssum, 8);
    ssum += __shfl_xor(ssum, 16);
    ssum += __shfl_xor(ssum, 32);
    float inv = 1.0f / ssum;
    #pragma unroll
    for (int p = 0; p < 8; ++p) {
      if (p < npass) {
        v[p] *= inv;
        #pragma unroll
        for (int e2 = 0; e2 < 8; ++e2) {
          int e = p * 8 + e2;
          if (e < deg) {
            float a = __shfl(v[p], (e2 << 3) | hg);
            int s = __shfl(sid, e);
            const ushort4 hv = *(const ushort4*)(hb + (long)s * 256 + l * 4);
            acc.x += a * bf2f(hv.x);
            acc.y += a * bf2f(hv.y);
            acc.z += a * bf2f(hv.z);
            acc.w += a * bf2f(hv.w);
          }
        }
      }
    }
  } else {
    float m = -1e30f;
    for (int base = 0; base < deg; base += 8) {
      int e = base + eo;
      float vv = -1e30f;
      if (e < deg) {
        int s = src[eidx[beg + e]];
        vv = el[(long)s * 8 + hh] + erv;
        vv = vv > 0.f ? vv : LEAKY * vv;
      }
      m = fmaxf(m, vv);
    }
    m = fmaxf(m, __shfl_xor(m, 8));
    m = fmaxf(m, __shfl_xor(m, 16));
    m = fmaxf(m, __shfl_xor(m, 32));
    float ssum = 0.f;
    for (int base = 0; base < deg; base += 8) {
      int e = base + eo;
      if (e < deg) {
        int s = src[eidx[beg + e]];
        float vv = el[(long)s * 8 + hh] + erv;
        vv = vv > 0.f ? vv : LEAKY * vv;
        ssum += __expf(vv - m);
      }
    }
    ssum += __shfl_xor(ssum, 8);
    ssum += __shfl_xor(ssum, 16);
    ssum += __shfl_xor(ssum, 32);
    float inv = 1.0f / ssum;
    for (int base = 0; base < deg; base += 8) {
      int e = base + eo;
      float a_me = 0.f;
      int s_me = 0;
      if (e < deg) {
        s_me = src[eidx[beg + e]];
        float vv = el[(long)s_me * 8 + hh] + erv;
        vv = vv > 0.f ? vv : LEAKY * vv;
        a_me = __expf(vv - m) * inv;
      }
      #pragma unroll
      for (int e2 = 0; e2 < 8; ++e2) {
        int e3 = base + e2;
        if (e3 < deg) {
          int srcl = (e2 << 3) | hg;
          float a = __shfl(a_me, srcl);
          int s = __shfl(s_me, srcl);
          const ushort4 hv = *(const ushort4*)(hb + (long)s * 256 + l * 4);
          acc.x += a * bf2f(hv.x);
          acc.y += a * bf2f(hv.y);
          acc.z += a * bf2f(hv.z);
          acc.w += a * bf2f(hv.w);
        }
      }
    }
  }
  *(float4*)op = acc;
}

// ---------------- per-graph mean pooling ----------------
__device__ __forceinline__ int lower_bound_i(const int* a, int n, int key) {
  int lo = 0, hi = n;
  while (lo < hi) {
    int mid = (lo + hi) >> 1;
    if (a[mid] < key) lo = mid + 1; else hi = mid;
  }
  return lo;
}

__global__ __launch_bounds__(256) void pool_k(const float* __restrict__ h,
                                              const int* __restrict__ gid,
                                              float* __restrict__ pooled, int N, int G) {
  int g = blockIdx.x;
  int t = threadIdx.x;
  __shared__ int s_lo, s_hi;
  if (t == 0) {
    s_lo = lower_bound_i(gid, N, g);
    s_hi = lower_bound_i(gid, N, g + 1);
  }
  __syncthreads();
  int lo = s_lo, hi = s_hi;
  float acc = 0.f;
  for (int n = lo; n < hi; ++n) acc += h[(long)n * 256 + t];
  float c = (float)(hi - lo);
  pooled[g * 256 + t] = acc / fmaxf(c, 1.f);
}

// ---------------- MLP ----------------
__global__ __launch_bounds__(256) void mlp_k(const float* __restrict__ pooled,
                                             const float* __restrict__ Wd1,
                                             const float* __restrict__ bd1,
                                             const float* __restrict__ Wd2,
                                             const float* __restrict__ bd2,
                                             float* __restrict__ outv, int G) {
  int g = blockIdx.x;
  int t = threadIdx.x;
  __shared__ float p_s[256];
  __shared__ float red[256];
  p_s[t] = pooled[g * 256 + t];
  __syncthreads();
  float acc0 = bd1[t], acc1 = bd1[t + 256];
  for (int k = 0; k < 256; ++k) {
    float pv = p_s[k];
    acc0 += pv * Wd1[k * 512 + t];
    acc1 += pv * Wd1[k * 512 + t + 256];
  }
  acc0 = fmaxf(acc0, 0.f);
  acc1 = fmaxf(acc1, 0.f);
  red[t] = acc0 * Wd2[t] + acc1 * Wd2[t + 256];
  __syncthreads();
  for (int off = 128; off > 0; off >>= 1) {
    if (t < off) red[t] += red[t + off];
    __syncthreads();
  }
  if (t == 0) outv[g] = red[0] + bd2[0];
}

extern "C" void kernel_launch(void* const* d_in, const int* in_sizes, int n_in,
                              void* d_out, int out_size, void* d_ws, size_t ws_size,
                              hipStream_t stream) {
  const float* X   = (const float*)d_in[0];
  const int*   src = (const int*)d_in[1];
  const int*   dst = (const int*)d_in[2];
  const int*   gid = (const int*)d_in[3];
  const float* W0  = (const float*)d_in[5];
  const float* al0 = (const float*)d_in[6];
  const float* ar0 = (const float*)d_in[7];
  const float* W1  = (const float*)d_in[8];
  const float* al1 = (const float*)d_in[9];
  const float* ar1 = (const float*)d_in[10];
  const float* Wd1 = (const float*)d_in[11];
  const float* bd1 = (const float*)d_in[12];
  const float* Wd2 = (const float*)d_in[13];
  const float* bd2 = (const float*)d_in[14];

  int E = in_sizes[1];
  int N = in_sizes[3];
  int G = out_size;

  float*    bAgg   = (float*)d_ws;                       // [N,256] f32 (agg out / gemm1 in)
  ushort_t* hb     = (ushort_t*)(bAgg + (size_t)N * 256);  // [N,256] bf16 h
  float*    el     = (float*)(hb + (size_t)N * 256);     // [N,8]
  float*    er     = el + (size_t)N * 8;                 // [N,8]
  float*    pooled = er + (size_t)N * 8;                 // [G,256]
  ushort_t* W0h    = (ushort_t*)(pooled + (size_t)G * 256);  // [256*128]
  ushort_t* W0l    = W0h + 256 * 128;
  ushort_t* W1h    = W0l + 256 * 128;                    // [256*256]
  ushort_t* W1l    = W1h + 256 * 256;
  int*      ptr    = (int*)(W1l + 256 * 256);            // [N+1]
  int*      cnt    = ptr + (N + 1);                      // [N]
  int*      eidx   = cnt + N;                            // [E]
  int*      bsum   = eidx + E;                           // [64]

  int nb = (N + 1023) / 1024;

  // CSR build over dst
  hipMemsetAsync(cnt, 0, (size_t)N * 4, stream);
  count_k<<<(E + 255) / 256, 256, 0, stream>>>(dst, cnt, E);
  scan1_k<<<nb, 1024, 0, stream>>>(cnt, ptr, bsum, N);
  scan2_k<<<1, 64, 0, stream>>>(bsum, nb);
  scan3_k<<<nb, 1024, 0, stream>>>(ptr, bsum, N, E);
  hipMemsetAsync(cnt, 0, (size_t)N * 4, stream);
  fill_k<<<(E + 255) / 256, 256, 0, stream>>>(dst, ptr, cnt, eidx, E);

  // W split/transpose (tiny)
  wsplit_k<<<(256 * 128 + 255) / 256, 256, 0, stream>>>(W0, W0h, W0l, 128);
  wsplit_k<<<(256 * 256 + 255) / 256, 256, 0, stream>>>(W1, W1h, W1l, 256);

  dim3 gg(N / 128, 4);
  // layer 0
  gemm_bf_k<<<gg, 256, 0, stream>>>(X, W0h, W0l, hb, N, 128);
  eler_k<<<(N * 8 + 255) / 256, 256, 0, stream>>>(hb, al0, ar0, el, er, N);
  agg_bf_k<<<(N + 3) / 4, 256, 0, stream>>>(hb, el, er, ptr, eidx, src, bAgg, N);
  // layer 1
  gemm_bf_k<<<gg, 256, 0, stream>>>(bAgg, W1h, W1l, hb, N, 256);
  eler_k<<<(N * 8 + 255) / 256, 256, 0, stream>>>(hb, al1, ar1, el, er, N);
  agg_bf_k<<<(N + 3) / 4, 256, 0, stream>>>(hb, el, er, ptr, eidx, src, bAgg, N);
  // readout + MLP
  pool_k<<<G, 256, 0, stream>>>(bAgg, gid, pooled, N, G);
  mlp_k<<<G, 256, 0, stream>>>(pooled, Wd1, bd1, Wd2, bd2, (float*)d_out, G);
}